// Round 4
// baseline (184.552 us; speedup 1.0000x reference)
//
#include <hip/hip_runtime.h>
#include <math.h>

#define SEQ   1024
#define DQ    256
#define DVD   512
#define NHH   16          // B*NH
#define EPSF  1e-6f
#define INV_SQRT_D 0.0625f   // 1/sqrt(256)

typedef __attribute__((ext_vector_type(8)))  short short8v;
typedef __attribute__((ext_vector_type(16))) float f32x16;

// ---- workspace layout (float offsets) ----
#define WS_FG    0                        // [16][1024]
#define WS_IG    (NHH*SEQ)                // [16][1024]
#define WS_ELIM  (2*NHH*SEQ)              // [16][1024]  exp(-m_t)
#define WS_HDEN  (3*NHH*SEQ)              // [16][1024]
#define WS_AT    (4*NHH*SEQ)              // [16][1024]  a_t = F_t - m_t
#define WS_CS    (5*NHH*SEQ)              // [16][1024]  c_s = i_s - F_s
#define WS_UT    (6*NHH*SEQ)              // [16][1024]  u_t (final C/n weight)
#define WS_AC    (7*NHH*SEQ)              // [16][16]
#define WS_BVEC  (WS_AC + NHH*16)         // [16][16][256]
#define WS_NST   (WS_BVEC + NHH*16*DQ)    // [16][16][256]
#define WS_SMALL_FLOATS (WS_NST + NHH*16*DQ)   // 246016 floats

#define QBF_OFF  ((size_t)WS_SMALL_FLOATS * 4)             // bytes (16-aligned)
#define KBF_OFF  (QBF_OFF + (size_t)NHH*SEQ*DQ*2)
#define VTB_OFF  (KBF_OFF + (size_t)NHH*SEQ*DQ*2)
#define KUT_OFF  (VTB_OFF + (size_t)NHH*DVD*SEQ*2)

__device__ __forceinline__ unsigned short f2bf(float f) {
  unsigned int u = __float_as_uint(f);
  return (unsigned short)((u + 0x7fffu + ((u >> 16) & 1u)) >> 16);
}

__device__ __forceinline__ void gl_lds16(const void* g, void* l) {
  __builtin_amdgcn_global_load_lds(
      (const __attribute__((address_space(1))) unsigned int*)g,
      (__attribute__((address_space(3))) unsigned int*)l, 16, 0, 0);
}

// ============================================================
// Gates: wave-shfl scans. Emits fg, ig, exp(-m), a_t, c_s, u_t, AC, m_out.
// ============================================================
__global__ __launch_bounds__(1024) void gates_kernel(
    const float* __restrict__ ipre, const float* __restrict__ fpre,
    float* __restrict__ ws, float* __restrict__ m_out) {
  const int hh = blockIdx.x;
  const int t  = threadIdx.x;
  const int lane = t & 63, wid = t >> 6;   // 16 waves
  __shared__ float Fs[SEQ];
  __shared__ float Ms[SEQ];
  __shared__ float wsum[16];
  __shared__ float wmax[16];

  const float fp = fpre[hh*SEQ + t];
  const float ip = ipre[hh*SEQ + t];
  const float flog = fminf(fp, 0.f) - log1pf(expf(-fabsf(fp)));

  // inclusive wave scan (sum) of flog
  float v = flog;
  #pragma unroll
  for (int off = 1; off < 64; off <<= 1) {
    float o = __shfl_up(v, off, 64);
    if (lane >= off) v += o;
  }
  if (lane == 63) wsum[wid] = v;
  __syncthreads();
  float woff = 0.f;
  #pragma unroll
  for (int i = 0; i < 16; ++i) { float s = wsum[i]; if (i < wid) woff += s; }
  const float F = v + woff;
  Fs[t] = F;

  // inclusive wave scan (max) of z = ip - F
  float zm = ip - F;
  #pragma unroll
  for (int off = 1; off < 64; off <<= 1) {
    float o = __shfl_up(zm, off, 64);
    if (lane >= off) zm = fmaxf(zm, o);
  }
  if (lane == 63) wmax[wid] = zm;
  __syncthreads();
  float zoff = -INFINITY;
  #pragma unroll
  for (int i = 0; i < 16; ++i) { float s = wmax[i]; if (i < wid) zoff = fmaxf(zoff, s); }
  const float zfull = fmaxf(zm, zoff);
  const float m_t = F + fmaxf(zfull, 0.f);
  Ms[t] = m_t;
  __syncthreads();

  const float m_prev = (t == 0) ? 0.f : Ms[t - 1];
  const float F_end = Fs[SEQ-1], m_end = Ms[SEQ-1];

  ws[WS_FG   + hh*SEQ + t] = expf(flog + m_prev - m_t);
  ws[WS_IG   + hh*SEQ + t] = expf(ip - m_t);
  ws[WS_ELIM + hh*SEQ + t] = expf(-m_t);
  ws[WS_AT   + hh*SEQ + t] = F - m_t;
  ws[WS_CS   + hh*SEQ + t] = ip - F;
  ws[WS_UT   + hh*SEQ + t] = expf(F_end - F + ip - m_end);  // exponent <= 0
  if (t == SEQ - 1) m_out[hh] = m_t;
  if ((t & 63) == 63) {
    const int c = t >> 6;
    const float Fprev  = (c == 0) ? 0.f : Fs[t - 64];
    const float mprevc = (c == 0) ? 0.f : Ms[t - 64];
    ws[WS_AC + hh*16 + c] = expf((F - Fprev) + (mprevc - m_t));
  }
}

// ============================================================
// Exact fp32 denominator pipeline (verified in rounds 1-2)
// ============================================================
__global__ __launch_bounds__(256) void bvec_kernel(
    const float* __restrict__ kin, float* __restrict__ ws) {
  const int hh = blockIdx.x >> 4;
  const int c  = blockIdx.x & 15;
  const int d  = threadIdx.x;
  __shared__ float lk[64][DQ];
  const int base = (hh*SEQ + c*64) * DQ;
  #pragma unroll 4
  for (int tt = 0; tt < 64; ++tt) lk[tt][d] = kin[base + tt*DQ + d];
  __syncthreads();
  float nb = 0.f;
  const float* fg = ws + WS_FG + hh*SEQ + c*64;
  const float* ig = ws + WS_IG + hh*SEQ + c*64;
  #pragma unroll 8
  for (int tt = 0; tt < 64; ++tt) nb = fg[tt]*nb + ig[tt]*lk[tt][d];
  ws[WS_BVEC + (hh*16 + c)*DQ + d] = nb;
}

__global__ __launch_bounds__(256) void nscan_kernel(
    float* __restrict__ ws, float* __restrict__ n_out) {
  const int hh = blockIdx.x;
  const int d  = threadIdx.x;
  float n = 0.f;
  for (int c = 0; c < 16; ++c) {
    ws[WS_NST + (hh*16 + c)*DQ + d] = n;
    n = ws[WS_AC + hh*16 + c]*n + ws[WS_BVEC + (hh*16 + c)*DQ + d];
  }
  n_out[hh*DQ + d] = n;
}

__global__ __launch_bounds__(256) void hden_kernel(
    const float* __restrict__ kin, const float* __restrict__ qin,
    float* __restrict__ ws) {
  const int hh = blockIdx.x >> 4;
  const int c  = blockIdx.x & 15;
  const int d  = threadIdx.x;
  __shared__ float pbuf[64][DQ];
  float n = ws[WS_NST + (hh*16 + c)*DQ + d];
  const int tbase = hh*SEQ + c*64;
  const int base  = tbase * DQ;
  #pragma unroll 4
  for (int tt = 0; tt < 64; ++tt) {
    const float fg = ws[WS_FG + tbase + tt];
    const float ig = ws[WS_IG + tbase + tt];
    n = fg*n + ig*kin[base + tt*DQ + d];
    pbuf[tt][d] = n * qin[base + tt*DQ + d];
  }
  __syncthreads();
  if (d < 64) {
    float s = 0.f;
    #pragma unroll 8
    for (int jj = 0; jj < DQ; ++jj) s += pbuf[d][(d + jj) & (DQ - 1)];
    const float qn = s * INV_SQRT_D;
    const float hd = fmaxf(fabsf(qn), ws[WS_ELIM + tbase + d]) + EPSF;
    ws[WS_HDEN + tbase + d] = hd;
  }
}

// ============================================================
// Cast: q_bf = bf16(q/16), k_bf = bf16(k)
// ============================================================
__global__ __launch_bounds__(256) void castqk_kernel(
    const float* __restrict__ q, const float* __restrict__ k,
    unsigned short* __restrict__ q_bf, unsigned short* __restrict__ k_bf) {
  const int total4 = NHH*SEQ*DQ/4;
  for (int i = blockIdx.x*blockDim.x + threadIdx.x; i < total4;
       i += gridDim.x*blockDim.x) {
    float4 a = ((const float4*)q)[i];
    float4 b = ((const float4*)k)[i];
    uint2 oq, ok;
    oq.x = (unsigned)f2bf(a.x*INV_SQRT_D) | ((unsigned)f2bf(a.y*INV_SQRT_D)<<16);
    oq.y = (unsigned)f2bf(a.z*INV_SQRT_D) | ((unsigned)f2bf(a.w*INV_SQRT_D)<<16);
    ok.x = (unsigned)f2bf(b.x) | ((unsigned)f2bf(b.y)<<16);
    ok.y = (unsigned)f2bf(b.z) | ((unsigned)f2bf(b.w)<<16);
    ((uint2*)q_bf)[i] = oq;
    ((uint2*)k_bf)[i] = ok;
  }
}

// ============================================================
// Transpose v[h][t][v] -> vt_bf[h][v][t]
// ============================================================
__global__ __launch_bounds__(256) void transpose_v_kernel(
    const float* __restrict__ v, unsigned short* __restrict__ vt_bf) {
  const int b = blockIdx.x;            // h*512 + tt*16 + vtile
  const int hh = b >> 9;
  const int tt = (b >> 4) & 31;
  const int vtile = b & 15;
  const int tx = threadIdx.x & 31, ty = threadIdx.x >> 5;
  __shared__ float tile[32][33];
  #pragma unroll
  for (int i = 0; i < 4; ++i)
    tile[ty + 8*i][tx] = v[((size_t)(hh*SEQ + tt*32 + ty + 8*i))*DVD + vtile*32 + tx];
  __syncthreads();
  #pragma unroll
  for (int i = 0; i < 4; ++i)
    vt_bf[((size_t)(hh*DVD + vtile*32 + ty + 8*i))*SEQ + tt*32 + tx] =
        f2bf(tile[tx][ty + 8*i]);
}

// ============================================================
// Transpose+weight: kut_bf[h][d][t] = bf16(u[t]*k[h][t][d])
// ============================================================
__global__ __launch_bounds__(256) void transpose_ku_kernel(
    const float* __restrict__ k, const float* __restrict__ ws,
    unsigned short* __restrict__ kut_bf) {
  const int b = blockIdx.x;            // h*256 + tt*8 + dtile
  const int hh = b >> 8;
  const int tt = (b >> 3) & 31;
  const int dtile = b & 7;
  const int tx = threadIdx.x & 31, ty = threadIdx.x >> 5;
  __shared__ float tile[32][33];
  #pragma unroll
  for (int i = 0; i < 4; ++i)
    tile[ty + 8*i][tx] = k[((size_t)(hh*SEQ + tt*32 + ty + 8*i))*DQ + dtile*32 + tx];
  __syncthreads();
  const float uu = ws[WS_UT + hh*SEQ + tt*32 + tx];
  #pragma unroll
  for (int i = 0; i < 4; ++i)
    kut_bf[((size_t)(hh*DQ + dtile*32 + ty + 8*i))*SEQ + tt*32 + tx] =
        f2bf(uu * tile[tx][ty + 8*i]);
}

// ============================================================
// Attention-style main kernel. Grid 512: (head, qtile 64, v-half 256),
// long tiles first. LDS = Vt 64KB + P 16KB = 80KB -> 2 blocks/CU.
// K,Q streamed from global (bf16, L2-hot); Vt staged issue-early.
// Denominator read from exact fp32 WS_HDEN.
// ============================================================
__global__ __launch_bounds__(512, 4) void attn_kernel(
    const unsigned short* __restrict__ q_bf,
    const unsigned short* __restrict__ k_bf,
    const unsigned short* __restrict__ vt_bf,
    const float* __restrict__ ws,
    float* __restrict__ h_out) {
  const int b = blockIdx.x;
  const int phase = b >> 8;
  const int idx = b & 255;
  const int hh = idx & 15;
  const int vh = (idx >> 4) & 1;
  const int qq = idx >> 5;
  const int qi = phase ? qq : (15 - qq);     // LPT: long q-tiles first
  const int nch = (qi >> 1) + 1;

  const int tid = threadIdx.x;
  const int w = tid >> 6, lane = tid & 63, l31 = lane & 31, hl = lane >> 5;
  const int tsub = w >> 2;        // 0..1: 32-row t-group
  const int sblk = w & 3;         // S-phase s-block
  const int vsub = w & 3;         // PV v-slice (64)

  __shared__ unsigned short Vtlds[256*128];  // 64 KB  [v][s], 16 slots/row
  __shared__ unsigned short Plds[64*128];    // 16 KB  [t][s], 16 slots/row

  const float* a_g  = ws + WS_AT;
  const float* c_g  = ws + WS_CS;
  const float* hd_g = ws + WS_HDEN;

  const int tq = qi*64 + tsub*32 + l31;      // lane's t-column
  const float a_t = a_g[hh*SEQ + tq];
  const int srow = sblk*32 + l31;
  const unsigned short* qp = q_bf + ((size_t)(hh*SEQ + tq))*DQ + hl*8;

  f32x16 acc0 = {}, acc1 = {};

  for (int c = 0; c < nch; ++c) {
    const int s0 = c*128;
    // ---- stage Vt(c): issued now, consumed after the barrier (in PV) ----
    #pragma unroll
    for (int p = 0; p < 8; ++p) {
      int u = p*512 + tid;
      int row = u >> 4, slot = u & 15;
      const unsigned short* src = vt_bf +
          ((size_t)(hh*DVD + vh*256 + row))*SEQ + s0 + ((slot ^ (row & 15))*8);
      gl_lds16(src, (char*)Vtlds + (p*8 + w)*1024);
    }
    // ---- S-phase: stream K,Q fragments from global ----
    const unsigned short* kp = k_bf + ((size_t)(hh*SEQ + s0 + srow))*DQ + hl*8;
    f32x16 sacc = {};
    #pragma unroll
    for (int d = 0; d < 16; ++d) {
      short8v kf = *(const short8v*)(kp + d*16);
      short8v qf = *(const short8v*)(qp + d*16);
      sacc = __builtin_amdgcn_mfma_f32_32x32x16_bf16(kf, qf, sacc, 0, 0, 0);
    }
    // ---- weight, mask, pack bf16, write to Plds (swizzled) ----
    const int prow = tsub*32 + l31;
    #pragma unroll
    for (int i = 0; i < 8; ++i) {
      const int r0 = 2*i;
      const int sl = sblk*32 + (r0 & 3) + 8*(r0 >> 2) + 4*hl;
      const int sg = s0 + sl;
      const float c0 = c_g[hh*SEQ + sg];
      const float c1 = c_g[hh*SEQ + sg + 1];
      const float p0 = (sg     <= tq) ? __expf(a_t + c0) * sacc[r0]     : 0.f;
      const float p1 = (sg + 1 <= tq) ? __expf(a_t + c1) * sacc[r0 + 1] : 0.f;
      unsigned int pk;
      asm volatile("v_cvt_pk_bf16_f32 %0, %1, %2" : "=v"(pk) : "v"(p0), "v"(p1));
      const int byte = sl*2;
      const int slot = byte >> 4, rem = byte & 15;
      *(unsigned int*)((char*)Plds + prow*256 + ((slot ^ (prow & 15))<<4) + rem) = pk;
    }
    __syncthreads();   // P visible; Vt(c) drained (arrived during S-phase)

    // ---- PV phase: acc[t][v] += P[t][s] * V[s][v] ----
    #pragma unroll
    for (int ss = 0; ss < 8; ++ss) {
      const int arow = tsub*32 + l31;
      short8v pa = *(const short8v*)&Plds[arow*128 + (((ss*2 + hl) ^ (arow & 15))*8)];
      const int vr0 = vsub*64 + l31;
      const int slotB = (ss*2 + hl) ^ (l31 & 15);
      short8v vb0 = *(const short8v*)&Vtlds[vr0*128 + slotB*8];
      short8v vb1 = *(const short8v*)&Vtlds[(vr0 + 32)*128 + slotB*8];
      acc0 = __builtin_amdgcn_mfma_f32_32x32x16_bf16(pa, vb0, acc0, 0, 0, 0);
      acc1 = __builtin_amdgcn_mfma_f32_32x32x16_bf16(pa, vb1, acc1, 0, 0, 0);
    }
    __syncthreads();   // protect Vt/Plds before next chunk's overwrite
  }

  // ---- epilogue: exact denominator from ws, write h ----
  #pragma unroll
  for (int r = 0; r < 16; ++r) {
    const int tl = tsub*32 + (r & 3) + 8*(r >> 2) + 4*hl;
    const int tg = qi*64 + tl;
    const float inv = 1.0f / hd_g[hh*SEQ + tg];
    const size_t ob = ((size_t)(hh*SEQ + tg))*DVD + vh*256 + vsub*64 + l31;
    h_out[ob]      = acc0[r] * inv;
    h_out[ob + 32] = acc1[r] * inv;
  }
}

// ============================================================
// C GEMM: C[h][d][v] = sum_t kut[h][d][t] * vt[h][v][t]
// ============================================================
__global__ __launch_bounds__(256, 2) void cgemm_kernel(
    const unsigned short* __restrict__ kut,
    const unsigned short* __restrict__ vt,
    float* __restrict__ C_out) {
  const int b = blockIdx.x;       // 16h x 2mt x 8nt
  const int hh = b >> 4;
  const int mt = (b >> 3) & 1;
  const int nt = b & 7;
  const int tid = threadIdx.x;
  const int w = tid >> 6, lane = tid & 63, l31 = lane & 31, hl = lane >> 5;
  const int mr = w >> 1;
  const int nc = w & 1;

  __shared__ unsigned short Alds[128*64];  // 16 KB, [d][t] rows 128B=8 slots
  __shared__ unsigned short Blds[64*64];   //  8 KB, [v][t]

  f32x16 acc0 = {}, acc1 = {};
  for (int c = 0; c < 16; ++c) {
    const int t0 = c*64;
    #pragma unroll
    for (int p = 0; p < 4; ++p) {
      int u = p*256 + tid; int row = u >> 3, slot = u & 7;
      const unsigned short* src = kut +
          ((size_t)(hh*DQ + mt*128 + row))*SEQ + t0 + ((slot ^ (row & 7))*8);
      gl_lds16(src, (char*)Alds + (p*4 + w)*1024);
    }
    #pragma unroll
    for (int p = 0; p < 2; ++p) {
      int u = p*256 + tid; int row = u >> 3, slot = u & 7;
      const unsigned short* src = vt +
          ((size_t)(hh*DVD + nt*64 + row))*SEQ + t0 + ((slot ^ (row & 7))*8);
      gl_lds16(src, (char*)Blds + (p*4 + w)*1024);
    }
    __syncthreads();
    #pragma unroll
    for (int ks = 0; ks < 4; ++ks) {
      const int br = nc*32 + l31;
      short8v bf_ = *(const short8v*)&Blds[br*64 + (((ks*2 + hl) ^ (br & 7))*8)];
      const int ar0 = mr*64 + l31, ar1 = ar0 + 32;
      short8v a0 = *(const short8v*)&Alds[ar0*64 + (((ks*2 + hl) ^ (ar0 & 7))*8)];
      short8v a1 = *(const short8v*)&Alds[ar1*64 + (((ks*2 + hl) ^ (ar1 & 7))*8)];
      acc0 = __builtin_amdgcn_mfma_f32_32x32x16_bf16(a0, bf_, acc0, 0, 0, 0);
      acc1 = __builtin_amdgcn_mfma_f32_32x32x16_bf16(a1, bf_, acc1, 0, 0, 0);
    }
    __syncthreads();
  }
  #pragma unroll
  for (int r = 0; r < 16; ++r) {
    const int dl = (r & 3) + 8*(r >> 2) + 4*hl;
    const int d0 = mt*128 + mr*64 + dl;
    const size_t ob = ((size_t)(hh*DQ + d0))*DVD + nt*64 + nc*32 + l31;
    C_out[ob]            = acc0[r];
    C_out[ob + 32*DVD]   = acc1[r];
  }
}

// ============================================================
extern "C" void kernel_launch(void* const* d_in, const int* in_sizes, int n_in,
                              void* d_out, int out_size, void* d_ws, size_t ws_size,
                              hipStream_t stream) {
  const float* q  = (const float*)d_in[0];
  const float* k  = (const float*)d_in[1];
  const float* v  = (const float*)d_in[2];
  const float* ip = (const float*)d_in[3];
  const float* fp = (const float*)d_in[4];

  float* h_out = (float*)d_out;                       // [16][1024][512]
  float* C_out = h_out + (size_t)NHH*SEQ*DVD;         // [16][256][512]
  float* n_out = C_out + (size_t)NHH*DQ*DVD;          // [16][256]
  float* m_out = n_out + NHH*DQ;                      // [16]
  float* ws    = (float*)d_ws;

  unsigned short* q_bf  = (unsigned short*)((char*)d_ws + QBF_OFF);
  unsigned short* k_bf  = (unsigned short*)((char*)d_ws + KBF_OFF);
  unsigned short* vt_bf = (unsigned short*)((char*)d_ws + VTB_OFF);
  unsigned short* kut   = (unsigned short*)((char*)d_ws + KUT_OFF);

  gates_kernel<<<NHH, 1024, 0, stream>>>(ip, fp, ws, m_out);
  castqk_kernel<<<2048, 256, 0, stream>>>(q, k, q_bf, k_bf);
  transpose_v_kernel<<<NHH*32*16, 256, 0, stream>>>(v, vt_bf);
  transpose_ku_kernel<<<NHH*32*8, 256, 0, stream>>>(k, ws, kut);
  bvec_kernel<<<NHH*16, 256, 0, stream>>>(k, ws);
  nscan_kernel<<<NHH, 256, 0, stream>>>(ws, n_out);
  hden_kernel<<<NHH*16, 256, 0, stream>>>(k, q, ws);
  attn_kernel<<<512, 512, 0, stream>>>(q_bf, k_bf, vt_bf, ws, h_out);
  cgemm_kernel<<<256, 256, 0, stream>>>(kut, vt_bf, C_out);
}

// Round 5
// 123.835 us; speedup vs baseline: 1.4903x; 1.4903x over previous
//
#include <hip/hip_runtime.h>
#include <math.h>

#define SEQ   1024
#define DQ    256
#define DVD   512
#define NHH   16          // B*NH
#define EPSF  1e-6f
#define INV_SQRT_D 0.0625f   // 1/sqrt(256)

typedef __attribute__((ext_vector_type(8)))  short short8v;
typedef __attribute__((ext_vector_type(16))) float f32x16;

// ---- workspace layout (float offsets) ----
#define WS_FG    0                        // [16][1024]
#define WS_IG    (NHH*SEQ)                // [16][1024]
#define WS_ELIM  (2*NHH*SEQ)              // [16][1024]  exp(-m_t)
#define WS_HDEN  (3*NHH*SEQ)              // [16][1024]
#define WS_AT    (4*NHH*SEQ)              // [16][1024]  a_t = F_t - m_t
#define WS_CS    (5*NHH*SEQ)              // [16][1024]  c_s = i_s - F_s
#define WS_UT    (6*NHH*SEQ)              // [16][1024]  u_t (final C/n weight)
#define WS_AC    (7*NHH*SEQ)              // [16][16]
#define WS_BVEC  (WS_AC + NHH*16)         // [16][16][256]
#define WS_NST   (WS_BVEC + NHH*16*DQ)    // [16][16][256]
#define WS_SMALL_FLOATS (WS_NST + NHH*16*DQ)

#define QBF_OFF  ((size_t)WS_SMALL_FLOATS * 4)             // bytes (16-aligned)
#define KBF_OFF  (QBF_OFF + (size_t)NHH*SEQ*DQ*2)
#define VTB_OFF  (KBF_OFF + (size_t)NHH*SEQ*DQ*2)
#define KUT_OFF  (VTB_OFF + (size_t)NHH*DVD*SEQ*2)

__device__ __forceinline__ unsigned short f2bf(float f) {
  unsigned int u = __float_as_uint(f);
  return (unsigned short)((u + 0x7fffu + ((u >> 16) & 1u)) >> 16);
}

__device__ __forceinline__ void gl_lds16(const void* g, void* l) {
  __builtin_amdgcn_global_load_lds(
      (const __attribute__((address_space(1))) unsigned int*)g,
      (__attribute__((address_space(3))) unsigned int*)l, 16, 0, 0);
}

// ============================================================
// Gates: wave-shfl scans. Emits fg, ig, exp(-m), a_t, c_s, u_t, AC, m_out.
// ============================================================
__global__ __launch_bounds__(1024) void gates_kernel(
    const float* __restrict__ ipre, const float* __restrict__ fpre,
    float* __restrict__ ws, float* __restrict__ m_out) {
  const int hh = blockIdx.x;
  const int t  = threadIdx.x;
  const int lane = t & 63, wid = t >> 6;   // 16 waves
  __shared__ float Fs[SEQ];
  __shared__ float Ms[SEQ];
  __shared__ float wsum[16];
  __shared__ float wmax[16];

  const float fp = fpre[hh*SEQ + t];
  const float ip = ipre[hh*SEQ + t];
  const float flog = fminf(fp, 0.f) - log1pf(expf(-fabsf(fp)));

  float v = flog;
  #pragma unroll
  for (int off = 1; off < 64; off <<= 1) {
    float o = __shfl_up(v, off, 64);
    if (lane >= off) v += o;
  }
  if (lane == 63) wsum[wid] = v;
  __syncthreads();
  float woff = 0.f;
  #pragma unroll
  for (int i = 0; i < 16; ++i) { float s = wsum[i]; if (i < wid) woff += s; }
  const float F = v + woff;
  Fs[t] = F;

  float zm = ip - F;
  #pragma unroll
  for (int off = 1; off < 64; off <<= 1) {
    float o = __shfl_up(zm, off, 64);
    if (lane >= off) zm = fmaxf(zm, o);
  }
  if (lane == 63) wmax[wid] = zm;
  __syncthreads();
  float zoff = -INFINITY;
  #pragma unroll
  for (int i = 0; i < 16; ++i) { float s = wmax[i]; if (i < wid) zoff = fmaxf(zoff, s); }
  const float zfull = fmaxf(zm, zoff);
  const float m_t = F + fmaxf(zfull, 0.f);
  Ms[t] = m_t;
  __syncthreads();

  const float m_prev = (t == 0) ? 0.f : Ms[t - 1];
  const float F_end = Fs[SEQ-1], m_end = Ms[SEQ-1];

  ws[WS_FG   + hh*SEQ + t] = expf(flog + m_prev - m_t);
  ws[WS_IG   + hh*SEQ + t] = expf(ip - m_t);
  ws[WS_ELIM + hh*SEQ + t] = expf(-m_t);
  ws[WS_AT   + hh*SEQ + t] = F - m_t;
  ws[WS_CS   + hh*SEQ + t] = ip - F;
  ws[WS_UT   + hh*SEQ + t] = expf(F_end - F + ip - m_end);
  if (t == SEQ - 1) m_out[hh] = m_t;
  if ((t & 63) == 63) {
    const int c = t >> 6;
    const float Fprev  = (c == 0) ? 0.f : Fs[t - 64];
    const float mprevc = (c == 0) ? 0.f : Ms[t - 64];
    ws[WS_AC + hh*16 + c] = expf((F - Fprev) + (mprevc - m_t));
  }
}

// ============================================================
// Role-fused prep kernel.
//  blocks [0,256): (head,chunk64) — read k ONCE: k_bf cast, bvec scan,
//                  kut = bf16(u_t * k) transposed [d][t].
//  blocks [256,768): (head, 32-row t-group) — v -> vt_bf transpose.
// ============================================================
__global__ __launch_bounds__(256) void prep_kernel(
    const float* __restrict__ kin, const float* __restrict__ vin,
    float* __restrict__ ws,
    unsigned short* __restrict__ k_bf, unsigned short* __restrict__ vt_bf,
    unsigned short* __restrict__ kut) {
  __shared__ float lk[64][257];        // 64.25 KB; role-b reuses
  const int b = blockIdx.x;
  if (b < 256) {
    const int hh = b >> 4, c = b & 15;
    const int d = threadIdx.x;
    const int tbase = hh*SEQ + c*64;
    const size_t base = (size_t)tbase * DQ;
    #pragma unroll 4
    for (int tt = 0; tt < 64; ++tt) {
      const float val = kin[base + (size_t)tt*DQ + d];
      lk[tt][d] = val;
      k_bf[base + (size_t)tt*DQ + d] = f2bf(val);
    }
    __syncthreads();
    const float* fg = ws + WS_FG + tbase;
    const float* ig = ws + WS_IG + tbase;
    float nb = 0.f;
    #pragma unroll 8
    for (int tt = 0; tt < 64; ++tt) nb = fg[tt]*nb + ig[tt]*lk[tt][d];
    ws[WS_BVEC + (hh*16 + c)*DQ + d] = nb;
    const float* u = ws + WS_UT + tbase;
    #pragma unroll
    for (int g = 0; g < 8; ++g) {
      short8v pk;
      #pragma unroll
      for (int j = 0; j < 8; ++j) {
        const int tt = g*8 + j;
        pk[j] = (short)f2bf(u[tt] * lk[tt][d]);
      }
      *(short8v*)(kut + ((size_t)(hh*DQ + d))*SEQ + c*64 + g*8) = pk;
    }
  } else {
    const int b2 = b - 256;            // 0..511
    const int hh = b2 >> 5, tg = b2 & 31;
    const int tx = threadIdx.x & 31, ty = threadIdx.x >> 5;
    float (*tile)[33] = (float(*)[33])lk;
    for (int vt = 0; vt < 16; ++vt) {
      #pragma unroll
      for (int i = 0; i < 4; ++i)
        tile[ty + 8*i][tx] =
            vin[((size_t)(hh*SEQ + tg*32 + ty + 8*i))*DVD + vt*32 + tx];
      __syncthreads();
      #pragma unroll
      for (int i = 0; i < 4; ++i)
        vt_bf[((size_t)(hh*DVD + vt*32 + ty + 8*i))*SEQ + tg*32 + tx] =
            f2bf(tile[tx][ty + 8*i]);
      __syncthreads();
    }
  }
}

// ============================================================
// nscan: 16-chunk affine scan of n (exact fp32)
// ============================================================
__global__ __launch_bounds__(256) void nscan_kernel(
    float* __restrict__ ws, float* __restrict__ n_out) {
  const int hh = blockIdx.x;
  const int d  = threadIdx.x;
  float n = 0.f;
  for (int c = 0; c < 16; ++c) {
    ws[WS_NST + (hh*16 + c)*DQ + d] = n;
    n = ws[WS_AC + hh*16 + c]*n + ws[WS_BVEC + (hh*16 + c)*DQ + d];
  }
  n_out[hh*DQ + d] = n;
}

// ============================================================
// hden (exact fp32) + fused q_bf cast (q/16 -> bf16)
// ============================================================
__global__ __launch_bounds__(256) void hden_kernel(
    const float* __restrict__ kin, const float* __restrict__ qin,
    float* __restrict__ ws, unsigned short* __restrict__ q_bf) {
  const int hh = blockIdx.x >> 4;
  const int c  = blockIdx.x & 15;
  const int d  = threadIdx.x;
  __shared__ float pbuf[64][DQ];
  float n = ws[WS_NST + (hh*16 + c)*DQ + d];
  const int tbase = hh*SEQ + c*64;
  const size_t base = (size_t)tbase * DQ;
  #pragma unroll 4
  for (int tt = 0; tt < 64; ++tt) {
    const float fg = ws[WS_FG + tbase + tt];
    const float ig = ws[WS_IG + tbase + tt];
    n = fg*n + ig*kin[base + (size_t)tt*DQ + d];
    const float qv = qin[base + (size_t)tt*DQ + d];
    q_bf[base + (size_t)tt*DQ + d] = f2bf(qv * INV_SQRT_D);
    pbuf[tt][d] = n * qv;
  }
  __syncthreads();
  if (d < 64) {
    float s = 0.f;
    #pragma unroll 8
    for (int jj = 0; jj < DQ; ++jj) s += pbuf[d][(d + jj) & (DQ - 1)];
    const float qn = s * INV_SQRT_D;
    const float hd = fmaxf(fabsf(qn), ws[WS_ELIM + tbase + d]) + EPSF;
    ws[WS_HDEN + tbase + d] = hd;
  }
}

// ============================================================
// Attention main kernel. 256 blocks = XCD-mapped (head, qpair, vhalf);
// each block: qtiles (p, 15-p) — constant 17 chunk-units of work.
// chunk=64; K/Vt double-buffered (144 KB); raw barriers with
// lgkmcnt-only mid-barrier so stage loads stay in flight.
// ============================================================
__global__ __launch_bounds__(512, 2) void attn_kernel(
    const unsigned short* __restrict__ q_bf,
    const unsigned short* __restrict__ k_bf,
    const unsigned short* __restrict__ vt_bf,
    const float* __restrict__ ws,
    float* __restrict__ h_out) {
  const int blk = blockIdx.x;
  const int xcd = blk & 7, slot = blk >> 3;
  const int hh  = xcd*2 + (slot & 1);      // 2 heads per XCD -> L2 affinity
  const int rest = slot >> 1;              // 0..15
  const int p   = rest & 7;
  const int vh  = rest >> 3;
  const int qS = p, qL = 15 - p;
  const int nchS = p + 1, nchL = 16 - p;

  const int tid = threadIdx.x;
  const int w = tid >> 6, lane = tid & 63, l31 = lane & 31, hl = lane >> 5;
  const int myq  = (w < 4) ? qL : qS;      // waves 0-3: long tile; 4-7: short
  const int wq   = w & 3;
  const int sblk = wq & 1, tsub = wq >> 1; // S-phase tile
  const int vsl  = wq;                     // PV v-slice (64 wide)
  const int prow0 = (w < 4) ? 0 : 64;
  const int nchW  = (w < 4) ? nchL : nchS;

  __shared__ unsigned short Kbuf[2][64*256];   // 2 x 32 KB  [s][d]
  __shared__ unsigned short Vtbuf[2][256*64];  // 2 x 32 KB  [v][s]
  __shared__ unsigned short Plds[128*64];      // 16 KB      [t(2 tiles)][s]

  const float* c_g  = ws + WS_CS   + hh*SEQ;
  const float* hd_g = ws + WS_HDEN + hh*SEQ;

  const int tq = myq*64 + tsub*32 + l31;       // lane's t-column (S-phase)
  const float a_t = ws[WS_AT + hh*SEQ + tq];
  const unsigned short* qp = q_bf + ((size_t)(hh*SEQ + tq))*DQ + hl*8;
  short8v qfrag[16];
  #pragma unroll
  for (int d = 0; d < 16; ++d) qfrag[d] = *(const short8v*)(qp + d*16);

  f32x16 a00 = {}, a01 = {}, a10 = {}, a11 = {};

  auto stageK = [&](int c) {
    const int cb = c & 1; const int s0 = c*64;
    #pragma unroll
    for (int p4 = 0; p4 < 4; ++p4) {
      const int u = p4*512 + tid;
      const int row = u >> 5, sl = u & 31;
      const unsigned short* src = k_bf +
          ((size_t)(hh*SEQ + s0 + row))*DQ + ((sl ^ (row & 31))*8);
      gl_lds16(src, (char*)&Kbuf[cb][0] + (p4*8 + w)*1024);
    }
  };
  auto stageV = [&](int c) {
    const int cb = c & 1; const int s0 = c*64;
    #pragma unroll
    for (int p4 = 0; p4 < 4; ++p4) {
      const int u = p4*512 + tid;
      const int row = u >> 3, sl = u & 7;
      const unsigned short* src = vt_bf +
          ((size_t)(hh*DVD + vh*256 + row))*SEQ + s0 + ((sl ^ (row & 7))*8);
      gl_lds16(src, (char*)&Vtbuf[cb][0] + (p4*8 + w)*1024);
    }
  };

  stageK(0); stageV(0);
  asm volatile("s_waitcnt vmcnt(0)" ::: "memory");
  __builtin_amdgcn_sched_barrier(0);
  __builtin_amdgcn_s_barrier();
  __builtin_amdgcn_sched_barrier(0);

  for (int c = 0; c < nchL; ++c) {
    const int cb = c & 1;
    const int s0 = c*64;
    if (c + 1 < nchL) { stageK(c+1); stageV(c+1); }   // in-flight across barrier
    const bool act = (c < nchW);
    if (act) {
      // ---- S-phase: S^T tile (32s x 32t) for my qtile ----
      const int srow = sblk*32 + l31;
      f32x16 sacc = {};
      __builtin_amdgcn_s_setprio(1);
      #pragma unroll
      for (int d = 0; d < 16; ++d) {
        short8v kf = *(const short8v*)
            &Kbuf[cb][srow*256 + (((d*2 + hl) ^ (srow & 31))*8)];
        sacc = __builtin_amdgcn_mfma_f32_32x32x16_bf16(kf, qfrag[d], sacc, 0, 0, 0);
      }
      __builtin_amdgcn_s_setprio(0);
      // ---- weight + mask + pack -> Plds (swizzled) ----
      const int prow = prow0 + tsub*32 + l31;
      #pragma unroll
      for (int i = 0; i < 8; ++i) {
        const int r0 = 2*i;
        const int sl = sblk*32 + (r0 & 3) + 8*(r0 >> 2) + 4*hl;
        const int sg = s0 + sl;
        const float c0 = c_g[sg], c1 = c_g[sg + 1];
        const float p0 = (sg     <= tq) ? __expf(a_t + c0) * sacc[r0]   : 0.f;
        const float p1 = (sg + 1 <= tq) ? __expf(a_t + c1) * sacc[r0+1] : 0.f;
        unsigned int pk;
        asm volatile("v_cvt_pk_bf16_f32 %0, %1, %2" : "=v"(pk) : "v"(p0), "v"(p1));
        const int byte = sl*2;
        *(unsigned int*)((char*)Plds + prow*128 +
            (((byte >> 4) ^ (prow & 7)) << 4) + (byte & 15)) = pk;
      }
    }
    // mid-barrier: drain LDS (P writes) only — stage loads stay outstanding
    asm volatile("s_waitcnt lgkmcnt(0)" ::: "memory");
    __builtin_amdgcn_sched_barrier(0);
    __builtin_amdgcn_s_barrier();
    __builtin_amdgcn_sched_barrier(0);
    if (act) {
      // ---- PV: acc[t][v] += P[t][s] * V[s][v] over this 64-s chunk ----
      const int ar0 = prow0 + l31, ar1 = ar0 + 32;
      const int vr0 = vsl*64 + l31, vr1 = vr0 + 32;
      __builtin_amdgcn_s_setprio(1);
      #pragma unroll
      for (int ks = 0; ks < 4; ++ks) {
        const int sl2 = ks*2 + hl;
        short8v pa0 = *(const short8v*)&Plds[ar0*64 + ((sl2 ^ (ar0 & 7))*8)];
        short8v pa1 = *(const short8v*)&Plds[ar1*64 + ((sl2 ^ (ar1 & 7))*8)];
        short8v vb0 = *(const short8v*)&Vtbuf[cb][vr0*64 + ((sl2 ^ (vr0 & 7))*8)];
        short8v vb1 = *(const short8v*)&Vtbuf[cb][vr1*64 + ((sl2 ^ (vr1 & 7))*8)];
        a00 = __builtin_amdgcn_mfma_f32_32x32x16_bf16(pa0, vb0, a00, 0, 0, 0);
        a01 = __builtin_amdgcn_mfma_f32_32x32x16_bf16(pa0, vb1, a01, 0, 0, 0);
        a10 = __builtin_amdgcn_mfma_f32_32x32x16_bf16(pa1, vb0, a10, 0, 0, 0);
        a11 = __builtin_amdgcn_mfma_f32_32x32x16_bf16(pa1, vb1, a11, 0, 0, 0);
      }
      __builtin_amdgcn_s_setprio(0);
    }
    // end-barrier: next chunk's bufs arrived; everyone done with P/V(c)
    asm volatile("s_waitcnt vmcnt(0)" ::: "memory");
    __builtin_amdgcn_sched_barrier(0);
    __builtin_amdgcn_s_barrier();
    __builtin_amdgcn_sched_barrier(0);
  }

  // ---- epilogue: divide by exact denominator, write h ----
  #pragma unroll
  for (int r = 0; r < 16; ++r) {
    const int tl = (r & 3) + 8*(r >> 2) + 4*hl;
    const int tg0 = myq*64 + tl;
    const int tg1 = tg0 + 32;
    const float i0 = 1.0f / hd_g[tg0];
    const float i1 = 1.0f / hd_g[tg1];
    const size_t ob0 = ((size_t)(hh*SEQ + tg0))*DVD + vh*256 + vsl*64 + l31;
    const size_t ob1 = ((size_t)(hh*SEQ + tg1))*DVD + vh*256 + vsl*64 + l31;
    h_out[ob0]      = a00[r] * i0;
    h_out[ob0 + 32] = a01[r] * i0;
    h_out[ob1]      = a10[r] * i1;
    h_out[ob1 + 32] = a11[r] * i1;
  }
}

// ============================================================
// C GEMM: C[h][d][v] = sum_t kut[h][d][t] * vt[h][v][t]
// ============================================================
__global__ __launch_bounds__(256, 2) void cgemm_kernel(
    const unsigned short* __restrict__ kut,
    const unsigned short* __restrict__ vt,
    float* __restrict__ C_out) {
  const int b = blockIdx.x;       // 16h x 2mt x 8nt
  const int hh = b >> 4;
  const int mt = (b >> 3) & 1;
  const int nt = b & 7;
  const int tid = threadIdx.x;
  const int w = tid >> 6, lane = tid & 63, l31 = lane & 31, hl = lane >> 5;
  const int mr = w >> 1;
  const int nc = w & 1;

  __shared__ unsigned short Alds[128*64];  // 16 KB, [d][t]
  __shared__ unsigned short Blds[64*64];   //  8 KB, [v][t]

  f32x16 acc0 = {}, acc1 = {};
  for (int c = 0; c < 16; ++c) {
    const int t0 = c*64;
    #pragma unroll
    for (int p = 0; p < 4; ++p) {
      int u = p*256 + tid; int row = u >> 3, slot = u & 7;
      const unsigned short* src = kut +
          ((size_t)(hh*DQ + mt*128 + row))*SEQ + t0 + ((slot ^ (row & 7))*8);
      gl_lds16(src, (char*)Alds + (p*4 + w)*1024);
    }
    #pragma unroll
    for (int p = 0; p < 2; ++p) {
      int u = p*256 + tid; int row = u >> 3, slot = u & 7;
      const unsigned short* src = vt +
          ((size_t)(hh*DVD + nt*64 + row))*SEQ + t0 + ((slot ^ (row & 7))*8);
      gl_lds16(src, (char*)Blds + (p*4 + w)*1024);
    }
    __syncthreads();
    #pragma unroll
    for (int ks = 0; ks < 4; ++ks) {
      const int br = nc*32 + l31;
      short8v bf_ = *(const short8v*)&Blds[br*64 + (((ks*2 + hl) ^ (br & 7))*8)];
      const int ar0 = mr*64 + l31, ar1 = ar0 + 32;
      short8v a0 = *(const short8v*)&Alds[ar0*64 + (((ks*2 + hl) ^ (ar0 & 7))*8)];
      short8v a1 = *(const short8v*)&Alds[ar1*64 + (((ks*2 + hl) ^ (ar1 & 7))*8)];
      acc0 = __builtin_amdgcn_mfma_f32_32x32x16_bf16(a0, bf_, acc0, 0, 0, 0);
      acc1 = __builtin_amdgcn_mfma_f32_32x32x16_bf16(a1, bf_, acc1, 0, 0, 0);
    }
    __syncthreads();
  }
  #pragma unroll
  for (int r = 0; r < 16; ++r) {
    const int dl = (r & 3) + 8*(r >> 2) + 4*hl;
    const int d0 = mt*128 + mr*64 + dl;
    const size_t ob = ((size_t)(hh*DQ + d0))*DVD + nt*64 + nc*32 + l31;
    C_out[ob]            = acc0[r];
    C_out[ob + 32*DVD]   = acc1[r];
  }
}

// ============================================================
extern "C" void kernel_launch(void* const* d_in, const int* in_sizes, int n_in,
                              void* d_out, int out_size, void* d_ws, size_t ws_size,
                              hipStream_t stream) {
  const float* q  = (const float*)d_in[0];
  const float* k  = (const float*)d_in[1];
  const float* v  = (const float*)d_in[2];
  const float* ip = (const float*)d_in[3];
  const float* fp = (const float*)d_in[4];

  float* h_out = (float*)d_out;                       // [16][1024][512]
  float* C_out = h_out + (size_t)NHH*SEQ*DVD;         // [16][256][512]
  float* n_out = C_out + (size_t)NHH*DQ*DVD;          // [16][256]
  float* m_out = n_out + NHH*DQ;                      // [16]
  float* ws    = (float*)d_ws;

  unsigned short* q_bf  = (unsigned short*)((char*)d_ws + QBF_OFF);
  unsigned short* k_bf  = (unsigned short*)((char*)d_ws + KBF_OFF);
  unsigned short* vt_bf = (unsigned short*)((char*)d_ws + VTB_OFF);
  unsigned short* kut   = (unsigned short*)((char*)d_ws + KUT_OFF);

  gates_kernel<<<NHH, 1024, 0, stream>>>(ip, fp, ws, m_out);
  prep_kernel<<<768, 256, 0, stream>>>(k, v, ws, k_bf, vt_bf, kut);
  nscan_kernel<<<NHH, 256, 0, stream>>>(ws, n_out);
  hden_kernel<<<NHH*16, 256, 0, stream>>>(k, q, ws, q_bf);
  attn_kernel<<<256, 512, 0, stream>>>(q_bf, k_bf, vt_bf, ws, h_out);
  cgemm_kernel<<<256, 256, 0, stream>>>(kut, vt_bf, C_out);
}